// Round 10
// baseline (436.498 us; speedup 1.0000x reference)
//
#include <hip/hip_runtime.h>

typedef __attribute__((ext_vector_type(8))) short bf16x8;
typedef __attribute__((ext_vector_type(4))) float f32x4;

__device__ __forceinline__ unsigned short f2bf(float f){
  unsigned int u = __builtin_bit_cast(unsigned int, f);
  u += 0x7fffu + ((u >> 16) & 1u);          // RTN-even
  return (unsigned short)(u >> 16);
}
__device__ __forceinline__ unsigned int pack2(float a, float b){
  return (unsigned int)f2bf(a) | ((unsigned int)f2bf(b) << 16);
}
__device__ __forceinline__ float bf_lo(unsigned int v){
  return __builtin_bit_cast(float, v << 16);
}
__device__ __forceinline__ float bf_hi(unsigned int v){
  return __builtin_bit_cast(float, v & 0xffff0000u);
}
__device__ __forceinline__ float lrelu(float x){ return x > 0.f ? x : 0.2f * x; }

#define GLOAD_LDS16(g, l) \
  __builtin_amdgcn_global_load_lds((const __attribute__((address_space(1))) unsigned int*)(g), \
                                   (__attribute__((address_space(3))) unsigned int*)(l), 16, 0, 0)

// ---------------- Kernel I: zero deg + W (f32 [k][c]) -> bf16 W^T [c][136] ---
__global__ __launch_bounds__(256) void k_init(const float* __restrict__ W,
                                              unsigned short* __restrict__ WbfT,
                                              int4* __restrict__ deg4, int n4){
  int i = blockIdx.x * 256 + threadIdx.x;
  if (i < n4){ int4 z; z.x=0; z.y=0; z.z=0; z.w=0; deg4[i] = z; }
  if (i < 128*128){
    int c = i & 127, k = i >> 7;
    WbfT[c * 136 + k] = f2bf(W[k * 128 + c]);
  }
}

// ---------------- Kernel A: h = x@W (bf16 MFMA, reg-staged bf16 LDS) --------
// 512 blocks x 512 thr (8 waves) -> 2 blocks/CU, 12-16 waves/CU.
// Wave = one 16-row slice. x loaded f32 -> regs (2-phase cur/nxt prefetch,
// compiler-managed waits), cvt to bf16 in-reg, ds_write into a SINGLE
// wave-private 4.35KB tile (wave-in-order LDS ops make 1 buffer safe),
// ds_read_b128 fragments, 32 MFMA. No barriers in the loop.
__global__ __launch_bounds__(512) void k_gemm(
    const float* __restrict__ x, const unsigned short* __restrict__ WbfT,
    const float* __restrict__ attS, const float* __restrict__ attD,
    unsigned short* __restrict__ h, float* __restrict__ aS, float* __restrict__ aD,
    int N, int nslices)
{
  __shared__ unsigned short Wt[128][136];     // 34816 B
  __shared__ unsigned short xt[8][16][136];   // 8 waves x 4352 B = 34816 B
  int tid = threadIdx.x;

  const char* wsrc = (const char*)WbfT;
  #pragma unroll
  for (int it = 0; it < 5; ++it){
    int i = it * 512 + tid;
    if (i < 2176) GLOAD_LDS16(wsrc + (size_t)i * 16, ((char*)Wt) + i * 16);
  }
  __syncthreads();   // once; loop below has no block-wide sync

  int wv = tid >> 6, lane = tid & 63;
  int lrow = lane & 15, lgrp = lane >> 4;
  int r2 = lane >> 5;        // row parity within a 2-row load pair
  int j  = lane & 31;        // 16B chunk within row

  int slice0 = (int)blockIdx.x * 8 + wv;
  int stride = (int)gridDim.x * 8;

  auto LOADS = [&](f32x4* v, int s){
    if (s >= nslices) s = nslices - 1;
    #pragma unroll
    for (int k = 0; k < 8; ++k){
      int gr = s * 16 + k * 2 + r2;
      if (gr >= N) gr = N - 1;
      v[k] = *(const f32x4*)(x + (size_t)gr * 128 + j * 4);
    }
  };

  auto COMP = [&](f32x4* v, int s){
    if (s >= nslices) return;                 // wave-uniform guard
    // cvt f32->bf16, deposit into wave-private tile
    #pragma unroll
    for (int k = 0; k < 8; ++k){
      uint2 u;
      u.x = pack2(v[k][0], v[k][1]);
      u.y = pack2(v[k][2], v[k][3]);
      *(uint2*)&xt[wv][k*2 + r2][j*4] = u;
    }
    // fragments (same-wave LDS ops are in-order; compiler inserts lgkmcnt)
    bf16x8 af[4];
    #pragma unroll
    for (int kt = 0; kt < 4; ++kt)
      af[kt] = *(const bf16x8*)&xt[wv][lrow][kt*32 + lgrp*8];

    f32x4 acc[8];
    #pragma unroll
    for (int ct = 0; ct < 8; ++ct){ acc[ct][0]=0.f; acc[ct][1]=0.f; acc[ct][2]=0.f; acc[ct][3]=0.f; }
    #pragma unroll
    for (int kt = 0; kt < 4; ++kt){
      #pragma unroll
      for (int ct = 0; ct < 8; ++ct){
        bf16x8 bw = *(const bf16x8*)&Wt[ct*16 + lrow][kt*32 + lgrp*8];
        acc[ct] = __builtin_amdgcn_mfma_f32_16x16x32_bf16(bw, af[kt], acc[ct], 0, 0, 0);
      }
    }

    // epilogue: lane owns row = s*16+lrow, cols ct*16 + lgrp*4 + (0..3)
    int row = s * 16 + lrow;
    float ps[4] = {0.f,0.f,0.f,0.f}, pd[4] = {0.f,0.f,0.f,0.f};
    #pragma unroll
    for (int ct = 0; ct < 8; ++ct){
      int hh = ct >> 1;
      f32x4 s4 = *(const f32x4*)(attS + ct*16 + lgrp*4);
      f32x4 d4 = *(const f32x4*)(attD + ct*16 + lgrp*4);
      #pragma unroll
      for (int g = 0; g < 4; ++g){
        ps[hh] += acc[ct][g] * s4[g];
        pd[hh] += acc[ct][g] * d4[g];
      }
    }
    #pragma unroll
    for (int hh = 0; hh < 4; ++hh){
      ps[hh] += __shfl_xor(ps[hh], 16, 64);
      ps[hh] += __shfl_xor(ps[hh], 32, 64);
      pd[hh] += __shfl_xor(pd[hh], 16, 64);
      pd[hh] += __shfl_xor(pd[hh], 32, 64);
    }
    if (lgrp == 0 && row < N){
      f32x4 vs, vd;
      #pragma unroll
      for (int hh = 0; hh < 4; ++hh){ vs[hh] = ps[hh]; vd[hh] = pd[hh]; }
      *(f32x4*)(aS + (size_t)row * 4) = vs;
      *(f32x4*)(aD + (size_t)row * 4) = vd;
    }
    if (row < N){
      unsigned short* hp = h + (size_t)row * 128 + lgrp * 4;
      #pragma unroll
      for (int ct = 0; ct < 8; ++ct){
        unsigned int u0 = (unsigned int)f2bf(acc[ct][0])
                        | ((unsigned int)f2bf(acc[ct][1]) << 16);
        unsigned int u1 = (unsigned int)f2bf(acc[ct][2])
                        | ((unsigned int)f2bf(acc[ct][3]) << 16);
        uint2 u; u.x = u0; u.y = u1;
        *(uint2*)(hp + ct * 16) = u;
      }
    }
  };

  f32x4 vA[8], vB[8];
  LOADS(vA, slice0);
  for (int s = slice0; s < nslices; s += 2 * stride){
    LOADS(vB, s + stride);          // prefetch phase-B slice under phase-A compute
    COMP(vA, s);
    LOADS(vA, s + 2 * stride);      // prefetch next phase-A slice under phase-B
    COMP(vB, s + stride);
  }
}

// ---------------- CSR build ----------------
__global__ __launch_bounds__(256) void k_hist(const int* __restrict__ dst, int E,
                                              int* __restrict__ deg){
  int e = blockIdx.x * 256 + threadIdx.x;
  if (e < E) atomicAdd(&deg[dst[e]], 1);
}

__global__ __launch_bounds__(256) void k_chunksum(const int* __restrict__ deg, int N,
                                                  int* __restrict__ bsum){
  __shared__ int sm[256];
  int tid = threadIdx.x;
  int base = blockIdx.x * 2048 + tid * 8;
  int s = 0;
  #pragma unroll
  for (int j = 0; j < 8; ++j) s += (base + j < N) ? deg[base + j] : 0;
  sm[tid] = s; __syncthreads();
  for (int off = 128; off > 0; off >>= 1){
    if (tid < off) sm[tid] += sm[tid + off];
    __syncthreads();
  }
  if (tid == 0) bsum[blockIdx.x] = sm[0];
}

__global__ __launch_bounds__(256) void k_scansums(int* __restrict__ bsum, int nb){
  __shared__ int sm[256];
  int tid = threadIdx.x;
  int carry = 0;
  for (int base = 0; base < nb; base += 256){
    int v = (base + tid < nb) ? bsum[base + tid] : 0;
    sm[tid] = v; __syncthreads();
    for (int off = 1; off < 256; off <<= 1){
      int t = (tid >= off) ? sm[tid - off] : 0;
      __syncthreads();
      sm[tid] += t;
      __syncthreads();
    }
    int incl = sm[tid];
    int total = sm[255];
    __syncthreads();
    if (base + tid < nb) bsum[base + tid] = carry + incl - v;
    carry += total;
  }
}

__global__ __launch_bounds__(256) void k_scanfinal(const int* __restrict__ deg,
    const int* __restrict__ bsum, int N, int E,
    int* __restrict__ rowptr, int* __restrict__ cursor){
  __shared__ int sm[256];
  int tid = threadIdx.x;
  int base = blockIdx.x * 2048 + tid * 8;
  int v[8];
  #pragma unroll
  for (int j = 0; j < 8; ++j) v[j] = (base + j < N) ? deg[base + j] : 0;
  int t = 0;
  #pragma unroll
  for (int j = 0; j < 8; ++j){ int x_ = v[j]; v[j] = t; t += x_; }
  sm[tid] = t; __syncthreads();
  for (int off = 1; off < 256; off <<= 1){
    int u = (tid >= off) ? sm[tid - off] : 0;
    __syncthreads();
    sm[tid] += u;
    __syncthreads();
  }
  int excl = sm[tid] - t;
  int off0 = bsum[blockIdx.x] + excl;
  #pragma unroll
  for (int j = 0; j < 8; ++j){
    if (base + j < N){
      int val = off0 + v[j];
      rowptr[base + j] = val;
      cursor[base + j] = val;
    }
  }
  if (blockIdx.x == 0 && tid == 0) rowptr[N] = E;
}

// ------- Kernel S: scatter src into CSR slot + precompute edge weights ------
__global__ __launch_bounds__(256) void k_scatter(const int* __restrict__ src,
    const int* __restrict__ dst, int E, int* __restrict__ cursor,
    const float* __restrict__ aS, const float* __restrict__ aD,
    int* __restrict__ csr, float* __restrict__ wexp){
  int e = blockIdx.x * 256 + threadIdx.x;
  if (e < E){
    int s = src[e], d = dst[e];
    int p = atomicAdd(&cursor[d], 1);
    csr[p] = s;
    f32x4 as = *(const f32x4*)(aS + (size_t)s * 4);
    f32x4 ad = *(const f32x4*)(aD + (size_t)d * 4);
    f32x4 w;
    #pragma unroll
    for (int hh = 0; hh < 4; ++hh) w[hh] = __expf(lrelu(as[hh] + ad[hh]));
    *(f32x4*)(wexp + (size_t)p * 4) = w;
  }
}

// ---------------- Kernel C: gather with precomputed weights + fc head -------
__global__ __launch_bounds__(256) void k_aggr(
    const uint4* __restrict__ h4, const float* __restrict__ aS,
    const float* __restrict__ aD, const int* __restrict__ rowptr,
    const int* __restrict__ csr, const float* __restrict__ wexp,
    const float* __restrict__ bias, const float* __restrict__ fcw,
    const float* __restrict__ fcb, float* __restrict__ out, int N)
{
  int lane = threadIdx.x & 63;
  int l16  = lane & 15;
  int node = ((int)blockIdx.x * 256 + (int)threadIdx.x) >> 4;
  if (node >= N) return;
  int head = l16 >> 2;

  float wself = __expf(lrelu(aS[node * 4 + head] + aD[node * 4 + head]));
  float wsum  = wself;

  float acc[8];
  {
    uint4 hv = h4[node * 16 + l16];
    acc[0] = wself * bf_lo(hv.x);  acc[1] = wself * bf_hi(hv.x);
    acc[2] = wself * bf_lo(hv.y);  acc[3] = wself * bf_hi(hv.y);
    acc[4] = wself * bf_lo(hv.z);  acc[5] = wself * bf_hi(hv.z);
    acc[6] = wself * bf_lo(hv.w);  acc[7] = wself * bf_hi(hv.w);
  }

  int rb = rowptr[node], re = rowptr[node + 1];
  for (int j = rb; j < re; j += 4){
    int i1 = (j + 1 < re) ? j + 1 : j;
    int i2 = (j + 2 < re) ? j + 2 : j;
    int i3 = (j + 3 < re) ? j + 3 : j;
    int s0 = csr[j], s1 = csr[i1], s2 = csr[i2], s3 = csr[i3];
    float m1 = (j + 1 < re) ? 1.f : 0.f;
    float m2 = (j + 2 < re) ? 1.f : 0.f;
    float m3 = (j + 3 < re) ? 1.f : 0.f;
    float w0 = wexp[(size_t)j  * 4 + head];
    float w1 = wexp[(size_t)i1 * 4 + head] * m1;
    float w2 = wexp[(size_t)i2 * 4 + head] * m2;
    float w3 = wexp[(size_t)i3 * 4 + head] * m3;
    uint4 v0 = h4[(size_t)s0 * 16 + l16];
    uint4 v1 = h4[(size_t)s1 * 16 + l16];
    uint4 v2 = h4[(size_t)s2 * 16 + l16];
    uint4 v3 = h4[(size_t)s3 * 16 + l16];
    wsum += w0 + w1 + w2 + w3;
    acc[0] += w0*bf_lo(v0.x) + w1*bf_lo(v1.x) + w2*bf_lo(v2.x) + w3*bf_lo(v3.x);
    acc[1] += w0*bf_hi(v0.x) + w1*bf_hi(v1.x) + w2*bf_hi(v2.x) + w3*bf_hi(v3.x);
    acc[2] += w0*bf_lo(v0.y) + w1*bf_lo(v1.y) + w2*bf_lo(v2.y) + w3*bf_lo(v3.y);
    acc[3] += w0*bf_hi(v0.y) + w1*bf_hi(v1.y) + w2*bf_hi(v2.y) + w3*bf_hi(v3.y);
    acc[4] += w0*bf_lo(v0.z) + w1*bf_lo(v1.z) + w2*bf_lo(v2.z) + w3*bf_lo(v3.z);
    acc[5] += w0*bf_hi(v0.z) + w1*bf_hi(v1.z) + w2*bf_hi(v2.z) + w3*bf_hi(v3.z);
    acc[6] += w0*bf_lo(v0.w) + w1*bf_lo(v1.w) + w2*bf_lo(v2.w) + w3*bf_lo(v3.w);
    acc[7] += w0*bf_hi(v0.w) + w1*bf_hi(v1.w) + w2*bf_hi(v2.w) + w3*bf_hi(v3.w);
  }

  float inv = 1.f / wsum;
  const float* bp = bias + l16 * 8;
  const float* fp = fcw  + l16 * 8;
  f32x4 b0 = *(const f32x4*)bp,      b1 = *(const f32x4*)(bp + 4);
  f32x4 f0 = *(const f32x4*)fp,      f1 = *(const f32x4*)(fp + 4);
  float p = 0.f;
  p += fmaxf(acc[0]*inv + b0[0], 0.f) * f0[0];
  p += fmaxf(acc[1]*inv + b0[1], 0.f) * f0[1];
  p += fmaxf(acc[2]*inv + b0[2], 0.f) * f0[2];
  p += fmaxf(acc[3]*inv + b0[3], 0.f) * f0[3];
  p += fmaxf(acc[4]*inv + b1[0], 0.f) * f1[0];
  p += fmaxf(acc[5]*inv + b1[1], 0.f) * f1[1];
  p += fmaxf(acc[6]*inv + b1[2], 0.f) * f1[2];
  p += fmaxf(acc[7]*inv + b1[3], 0.f) * f1[3];
  #pragma unroll
  for (int m = 1; m < 16; m <<= 1) p += __shfl_xor(p, m, 64);
  if (l16 == 0) out[node] = 1.f / (1.f + __expf(-(p + fcb[0])));
}

extern "C" void kernel_launch(void* const* d_in, const int* in_sizes, int n_in,
                              void* d_out, int out_size, void* d_ws, size_t ws_size,
                              hipStream_t stream) {
  const float* x    = (const float*)d_in[0];
  const int*   ei   = (const int*)  d_in[1];
  const float* W    = (const float*)d_in[2];
  const float* attS = (const float*)d_in[3];
  const float* attD = (const float*)d_in[4];
  const float* bias = (const float*)d_in[5];
  const float* fcw  = (const float*)d_in[6];
  const float* fcb  = (const float*)d_in[7];

  int N = in_sizes[0] / 128;
  int E = in_sizes[1] / 2;
  const int* srcA = ei;
  const int* dstA = ei + E;

  char* ws = (char*)d_ws;
  size_t off = 0;
  auto alloc = [&](size_t bytes) -> void* {
    void* p = ws + off;
    off += (bytes + 255) & ~(size_t)255;
    return p;
  };
  unsigned short* h  = (unsigned short*)alloc((size_t)N * 128 * 2);
  float* aS   = (float*)alloc((size_t)N * 4 * 4);
  float* aD   = (float*)alloc((size_t)N * 4 * 4);
  int* deg    = (int*)alloc((size_t)N * 4);
  int* rowptr = (int*)alloc(((size_t)N + 1) * 4);
  int* cursor = (int*)alloc((size_t)N * 4);
  int* csr    = (int*)alloc((size_t)E * 4);
  float* wexp = (float*)alloc((size_t)E * 4 * 4);
  int* bsum   = (int*)alloc(4096);
  unsigned short* WbfT = (unsigned short*)alloc(128 * 136 * 2);

  int n4 = (N + 3) / 4;
  int ninit = (n4 > 16384) ? n4 : 16384;
  k_init<<<(ninit + 255) / 256, 256, 0, stream>>>(W, WbfT, (int4*)deg, n4);
  int nslices = (N + 15) / 16;
  k_gemm<<<512, 512, 0, stream>>>(x, WbfT, attS, attD, h, aS, aD, N, nslices);
  k_hist<<<(E + 255) / 256, 256, 0, stream>>>(dstA, E, deg);
  int nb = (N + 2047) / 2048;
  k_chunksum<<<nb, 256, 0, stream>>>(deg, N, bsum);
  k_scansums<<<1, 256, 0, stream>>>(bsum, nb);
  k_scanfinal<<<nb, 256, 0, stream>>>(deg, bsum, N, E, rowptr, cursor);
  k_scatter<<<(E + 255) / 256, 256, 0, stream>>>(srcA, dstA, E, cursor, aS, aD,
                                                 csr, wexp);
  k_aggr<<<(N + 15) / 16, 256, 0, stream>>>((const uint4*)h, aS, aD, rowptr, csr,
                                            wexp, bias, fcw, fcb, (float*)d_out, N);
}